// Round 15
// baseline (57.658 us; speedup 1.0000x reference)
//
#include <hip/hip_runtime.h>

// SE(2) depthwise group conv via bf16 MFMA (fp32 accum), Delta-packed,
// LDS-transpose epilogue + NT stores of FULL 512B output rows.
//
// out[b,c,t,y,x] = sum_{o,dy,dx} W[c,t,o,dy,dx] * x[b,c,o,y+dy-2,x+dx-2]
// GEMM per (b,c): D[m=16 pix][n=(t,Dlt)], Dlt in {0,1} packs TWO output rows
// per MFMA. K = 32 row-taps tr=(dyr 0..5, dx 0..4) x 8 o = 256:
// B[(dyr,dx,o)][(t,Dlt)] = w[t][dyr-Dlt, dx] (0 OOR; tr>=30 pad).
// mfma_f32_16x16x32_bf16: A lane: row=l&15 (pixel x-offset), tap tr=cc*4+g.
//   D lane l: col=l&15=(t+8*Dlt), row=(l>>4)*4+reg = pixel.
// Block = 16 rows x 128 cols (FULL width) of one (b,c); 4 waves;
// 16 s-iters x 8 cc = 128 MFMA/wave. Grid 2048, XCD-chunked swizzle.
// LDS union 42240 B (3 blocks/CU):
//   stage: [20 r][132 c][8 o] bf16 = 42240 B (during compute)
//   epil : f32 [4 t][16 y pitch 132] = 33856 B, two passes (t<4, t>=4)
// Store: one NT f32x4 x 32 lanes = 512 B = one complete t-plane row.

typedef short bf16x8 __attribute__((ext_vector_type(8)));
typedef float f32x4 __attribute__((ext_vector_type(4)));

#define EPIL_TS 2116   // floats per t-plane (16*132 + 4)
#define EPIL_RP 132    // row pitch in floats

__device__ inline unsigned short f2bf(float f) {   // RNE f32->bf16
    unsigned int u = __float_as_uint(f);
    u += 0x7fffu + ((u >> 16) & 1u);
    return (unsigned short)(u >> 16);
}
__device__ inline unsigned pk2(float a, float b) {
    return (unsigned)f2bf(a) | ((unsigned)f2bf(b) << 16);
}

// cos/sin of 2*pi*t/8, f32. NN-rounding margins >=0.035 -> table-vs-libm safe.
__device__ __constant__ float CA8[8] = {1.0f, 0.70710678f, 0.0f, -0.70710678f,
                                        -1.0f, -0.70710678f, 0.0f, 0.70710678f};
__device__ __constant__ float SA8[8] = {0.0f, 0.70710678f, 1.0f, 0.70710678f,
                                        0.0f, -0.70710678f, -1.0f, -0.70710678f};

__device__ inline float rot_w(const float* __restrict__ kern, int c, int t,
                              int o, int dy, int dx) {
    float ca = CA8[t], sa = SA8[t];
    float xx = (float)dx - 2.0f, yy = (float)dy - 2.0f;
    int iy = (int)rintf(sa * xx + ca * yy + 2.0f);  // RNE == jnp.round
    int ix = (int)rintf(ca * xx - sa * yy + 2.0f);
    if (iy >= 0 && iy < 5 && ix >= 0 && ix < 5) {
        int tp = (o - t) & 7;
        return kern[(c * 8 + tp) * 25 + iy * 5 + ix];
    }
    return 0.0f;
}

// wtab2[((c*16 + n16)*32 + tr)*8 + o], n16 = t + 8*Dlt; 131072 bf16 = 256 KB
__global__ __launch_bounds__(256)
void build_w2(const float* __restrict__ kern, unsigned short* __restrict__ wtab) {
    int e = blockIdx.x * 256 + threadIdx.x;
    if (e >= 131072) return;
    int o   = e & 7;
    int tr  = (e >> 3) & 31;
    int n16 = (e >> 8) & 15;
    int c   = e >> 12;
    int t   = n16 & 7, dlt = n16 >> 3;
    float w = 0.0f;
    if (tr < 30) {
        int dyr = tr / 5, dx = tr - 5 * dyr;
        int dy  = dyr - dlt;
        if (dy >= 0 && dy < 5) w = rot_w(kern, c, t, o, dy, dx);
    }
    wtab[e] = f2bf(w);
}

template <bool TAB>
__global__ __launch_bounds__(256)
void se2_mfma(const float* __restrict__ x, const float* __restrict__ kern,
              const unsigned short* __restrict__ wtab, float* __restrict__ out) {
    // union: stage 42240 B (shorts) / epil 33856 B (f32) / fallback ldsw
    __shared__ __align__(16) float ldsbuf[10560];
    unsigned short* stage = reinterpret_cast<unsigned short*>(ldsbuf);
    float* epil = ldsbuf;

    // XCD-chunked bijective swizzle: 2048 blocks, 8 XCDs, 256 per XCD.
    const int bid = (blockIdx.x & 7) * 256 + (blockIdx.x >> 3);
    const int ys  = bid & 7;           // 8 row-strips of 16
    const int bc  = bid >> 3;          // b*32 + c
    const int c   = bc & 31;
    const int Y0  = ys * 16;
    const int tid = threadIdx.x;

    const int lane = tid & 63;
    const int wv   = tid >> 6;         // wave: rows [wv*4, wv*4+4)
    const int g    = lane >> 4;        // k-group (4 row-taps)
    const int m16  = lane & 15;        // A-row pixel / D-col n16

    const float* xbase = x + (size_t)bc * 131072;

    // stage chunk e -> (r = e/132, col = e%132); 2640 chunks total
    auto loadch = [&](int e, float (&v)[8]) {
        int r = e / 132, col = e - r * 132;
        int gy = Y0 - 2 + r, gx = col - 2;
        if (gy >= 0 && gy < 128 && gx >= 0 && gx < 128) {
            const float* src = xbase + gy * 128 + gx;
#pragma unroll
            for (int o = 0; o < 8; ++o) v[o] = src[o * 16384];
        } else {
#pragma unroll
            for (int o = 0; o < 8; ++o) v[o] = 0.0f;
        }
    };
    auto packch = [&](int e, const float (&v)[8]) {
        *reinterpret_cast<uint4*>(&stage[e * 8]) =
            make_uint4(pk2(v[0], v[1]), pk2(v[2], v[3]),
                       pk2(v[4], v[5]), pk2(v[6], v[7]));
    };

    float sA[8], sB[8];
    loadch(tid, sA);           // first loads issued before wfrag reads
    loadch(tid + 256, sB);

    bf16x8 wfrag[8];
    int    tapoff[8];
#pragma unroll
    for (int cc = 0; cc < 8; ++cc) {
        int tr  = cc * 4 + g;
        int trc = tr < 30 ? tr : 29;   // A addr clamp (B weight is zero there)
        int dyr = trc / 5, dx = trc - 5 * dyr;
        tapoff[cc] = (dyr * 132 + dx) * 8;         // in shorts
        if constexpr (TAB)
            wfrag[cc] = *reinterpret_cast<const bf16x8*>(
                &wtab[((c * 16 + m16) * 32 + tr) * 8]);
    }

    if constexpr (!TAB) {
        // fallback: build [16 n][32 tr][8 o] table beyond first stage writes
        unsigned short* ldsw = stage + 16384;
        for (int e = tid; e < 4096; e += 256) {
            int o = e & 7, tr = (e >> 3) & 31, n16 = e >> 8;
            int t = n16 & 7, dlt = n16 >> 3;
            float w = 0.0f;
            if (tr < 30) {
                int dyr = tr / 5, dx = tr - 5 * dyr;
                int dy  = dyr - dlt;
                if (dy >= 0 && dy < 5) w = rot_w(kern, c, t, o, dy, dx);
            }
            ldsw[e] = f2bf(w);
        }
        __syncthreads();
#pragma unroll
        for (int cc = 0; cc < 8; ++cc)
            wfrag[cc] = *reinterpret_cast<const bf16x8*>(
                &ldsw[(m16 * 32 + cc * 4 + g) * 8]);
        __syncthreads();   // wfrag reads done before packch overwrites region
    }

    packch(tid, sA);
    packch(tid + 256, sB);
    // remaining 4 pairs of rounds + 80-chunk tail, 2 loads in flight each
#pragma unroll 1
    for (int kp = 1; kp < 5; ++kp) {
        loadch(tid + kp * 512, sA);
        loadch(tid + kp * 512 + 256, sB);
        packch(tid + kp * 512, sA);
        packch(tid + kp * 512 + 256, sB);
    }
    if (tid < 80) { loadch(2560 + tid, sA); packch(2560 + tid, sA); }
    __syncthreads();

    // ---- compute: 16 s-iters (pr = s>>3 row-pair, xq = s&7) ----
    f32x4 acc[16];
#pragma unroll
    for (int s = 0; s < 16; ++s) {
        acc[s] = (f32x4){0.f, 0.f, 0.f, 0.f};
        const int yl = wv * 4 + (s >> 3) * 2;
        const int baseS = (yl * 132 + (s & 7) * 16 + m16) * 8;
#pragma unroll
        for (int cc = 0; cc < 8; ++cc) {
            bf16x8 xf = *reinterpret_cast<const bf16x8*>(&stage[baseS + tapoff[cc]]);
            acc[s] = __builtin_amdgcn_mfma_f32_16x16x32_bf16(xf, wfrag[cc], acc[s], 0, 0, 0);
        }
    }
    __syncthreads();   // all waves done reading stage; epil may overwrite

    // ---- epilogue: two passes of 4 t-planes each; NT 512B-row stores ----
    const int t_o = m16 & 7, dlt = m16 >> 3;
    float* outb = out + (size_t)bc * 131072;

#pragma unroll
    for (int p = 0; p < 2; ++p) {
        if (p) __syncthreads();        // pass-1 writes wait for pass-0 reads
        if ((t_o >> 2) == p) {
#pragma unroll
            for (int s = 0; s < 16; ++s) {
                int y  = wv * 4 + (s >> 3) * 2 + dlt;
                int xx = (s & 7) * 16 + g * 4;
                *reinterpret_cast<f32x4*>(
                    &epil[(t_o & 3) * EPIL_TS + y * EPIL_RP + xx]) = acc[s];
            }
        }
        __syncthreads();
#pragma unroll
        for (int j = 0; j < 8; ++j) {
            int idx = j * 256 + tid;
            int x4  = idx & 31;            // 32 f32x4 = one 512B row
            int y   = (idx >> 5) & 15;
            int t4  = idx >> 9;            // 0..3
            f32x4 v = *reinterpret_cast<const f32x4*>(
                &epil[t4 * EPIL_TS + y * EPIL_RP + x4 * 4]);
            __builtin_nontemporal_store(v, reinterpret_cast<f32x4*>(
                outb + (size_t)(p * 4 + t4) * 16384 +
                (size_t)(Y0 + y) * 128 + x4 * 4));
        }
    }
}

extern "C" void kernel_launch(void* const* d_in, const int* in_sizes, int n_in,
                              void* d_out, int out_size, void* d_ws, size_t ws_size,
                              hipStream_t stream) {
    const float* x    = (const float*)d_in[0];
    const float* kern = (const float*)d_in[1];
    float* out = (float*)d_out;
    dim3 block(256);
    if (ws_size >= 131072 * sizeof(unsigned short)) {
        unsigned short* wtab = (unsigned short*)d_ws;
        build_w2<<<dim3(512), block, 0, stream>>>(kern, wtab);
        se2_mfma<true><<<dim3(2048), block, 0, stream>>>(x, kern, wtab, out);
    } else {
        se2_mfma<false><<<dim3(2048), block, 0, stream>>>(x, kern, nullptr, out);
    }
}

// Round 16
// 52.346 us; speedup vs baseline: 1.1015x; 1.1015x over previous
//
#include <hip/hip_runtime.h>

// SE(2) depthwise group conv via bf16 MFMA (fp32 accum), Delta-packed,
// LDS-transpose epilogue (wave-private) + NT 256B stores.
//
// out[b,c,t,y,x] = sum_{o,dy,dx} W[c,t,o,dy,dx] * x[b,c,o,y+dy-2,x+dx-2]
// GEMM per (b,c): D[m=16 pix][n=(t,Dlt)], Dlt in {0,1} packs TWO output rows
// per MFMA. K = 32 row-taps tr=(dyr 0..5, dx 0..4) x 8 o = 256:
// B[(dyr,dx,o)][(t,Dlt)] = w[t][dyr-Dlt, dx] (0 OOR; tr>=30 pad).
// mfma_f32_16x16x32_bf16: A lane: row=l&15 (pixel x-offset), tap tr=cc*4+g.
//   D lane l: col=l&15=(t+8*Dlt), row=(l>>4)*4+reg = pixel -> f32x4.
// Block = 16 rows x 64 cols of one (b,c); 4 waves; 64 MFMA/wave.
// R16 vs R14: (1) ALL staging loads issued before packing (1 exposed
// latency, not 4); (2) epilogue is wave-aligned: wave wv writes AND reads
// only rows wv*4..wv*4+3 of epil -> single post-compute barrier, waves
// drift independently through transpose+store (smoother HBM writes).
// LDS union 34944 B: stage [20][68][8] bf16 = 21760 B; epil f32
// [8 t][16 y pitch 68]. Grid 4096, XCD-chunked swizzle.

typedef short bf16x8 __attribute__((ext_vector_type(8)));
typedef float f32x4 __attribute__((ext_vector_type(4)));

#define EPIL_TS 1092   // floats per t-plane (16*68 + 4)
#define EPIL_RP 68     // row pitch in floats

__device__ inline unsigned short f2bf(float f) {   // RNE f32->bf16
    unsigned int u = __float_as_uint(f);
    u += 0x7fffu + ((u >> 16) & 1u);
    return (unsigned short)(u >> 16);
}
__device__ inline unsigned pk2(float a, float b) {
    return (unsigned)f2bf(a) | ((unsigned)f2bf(b) << 16);
}

// cos/sin of 2*pi*t/8, f32. NN-rounding margins >=0.035 -> table-vs-libm safe.
__device__ __constant__ float CA8[8] = {1.0f, 0.70710678f, 0.0f, -0.70710678f,
                                        -1.0f, -0.70710678f, 0.0f, 0.70710678f};
__device__ __constant__ float SA8[8] = {0.0f, 0.70710678f, 1.0f, 0.70710678f,
                                        0.0f, -0.70710678f, -1.0f, -0.70710678f};

__device__ inline float rot_w(const float* __restrict__ kern, int c, int t,
                              int o, int dy, int dx) {
    float ca = CA8[t], sa = SA8[t];
    float xx = (float)dx - 2.0f, yy = (float)dy - 2.0f;
    int iy = (int)rintf(sa * xx + ca * yy + 2.0f);  // RNE == jnp.round
    int ix = (int)rintf(ca * xx - sa * yy + 2.0f);
    if (iy >= 0 && iy < 5 && ix >= 0 && ix < 5) {
        int tp = (o - t) & 7;
        return kern[(c * 8 + tp) * 25 + iy * 5 + ix];
    }
    return 0.0f;
}

// wtab2[((c*16 + n16)*32 + tr)*8 + o], n16 = t + 8*Dlt; 131072 bf16 = 256 KB
__global__ __launch_bounds__(256)
void build_w2(const float* __restrict__ kern, unsigned short* __restrict__ wtab) {
    int e = blockIdx.x * 256 + threadIdx.x;
    if (e >= 131072) return;
    int o   = e & 7;
    int tr  = (e >> 3) & 31;
    int n16 = (e >> 8) & 15;
    int c   = e >> 12;
    int t   = n16 & 7, dlt = n16 >> 3;
    float w = 0.0f;
    if (tr < 30) {
        int dyr = tr / 5, dx = tr - 5 * dyr;
        int dy  = dyr - dlt;
        if (dy >= 0 && dy < 5) w = rot_w(kern, c, t, o, dy, dx);
    }
    wtab[e] = f2bf(w);
}

template <bool TAB>
__global__ __launch_bounds__(256)
void se2_mfma(const float* __restrict__ x, const float* __restrict__ kern,
              const unsigned short* __restrict__ wtab, float* __restrict__ out) {
    // union: stage (21760 B, shorts) / epil (34944 B, f32) / fallback ldsw
    __shared__ __align__(16) float ldsbuf[8 * EPIL_TS];   // 34944 B
    unsigned short* stage = reinterpret_cast<unsigned short*>(ldsbuf);
    float* epil = ldsbuf;

    // XCD-chunked bijective swizzle: 4096 blocks, 8 XCDs, 512 per XCD.
    const int bid = (blockIdx.x & 7) * 512 + (blockIdx.x >> 3);
    const int xh2 = bid & 1;           // x half: cols 0-63 / 64-127
    const int ys  = (bid >> 1) & 7;    // 8 row-strips of 16
    const int bc  = bid >> 4;          // b*32 + c
    const int c   = bc & 31;
    const int X0  = xh2 * 64, Y0 = ys * 16;
    const int tid = threadIdx.x;

    const int lane = tid & 63;
    const int wv   = tid >> 6;         // wave: rows [wv*4, wv*4+4)
    const int g    = lane >> 4;        // k-group (4 row-taps)
    const int m16  = lane & 15;        // A-row pixel / D-col n16

    const float* xbase = x + (size_t)bc * 131072;

    // stage chunk e -> (r = e/68, col = e%68); 1360 chunks total
    auto loadch = [&](int e, float (&v)[8]) {
        int r = e / 68, col = e - r * 68;
        int gy = Y0 - 2 + r, gx = X0 - 2 + col;
        if (gy >= 0 && gy < 128 && gx >= 0 && gx < 128) {
            const float* src = xbase + gy * 128 + gx;
#pragma unroll
            for (int o = 0; o < 8; ++o) v[o] = src[o * 16384];
        } else {
#pragma unroll
            for (int o = 0; o < 8; ++o) v[o] = 0.0f;
        }
    };
    auto packch = [&](int e, const float (&v)[8]) {
        *reinterpret_cast<uint4*>(&stage[e * 8]) =
            make_uint4(pk2(v[0], v[1]), pk2(v[2], v[3]),
                       pk2(v[4], v[5]), pk2(v[6], v[7]));
    };

    // ---- issue ALL staging loads up front (one exposed HBM latency) ----
    float v0[8], v1[8], v2[8], v3[8], v4[8], v5[8];
    loadch(tid, v0);
    loadch(tid + 256, v1);
    loadch(tid + 512, v2);
    loadch(tid + 768, v3);
    loadch(tid + 1024, v4);
    if (tid < 80) loadch(tid + 1280, v5);

    bf16x8 wfrag[8];
    int    tapoff[8];
#pragma unroll
    for (int cc = 0; cc < 8; ++cc) {
        int tr  = cc * 4 + g;
        int trc = tr < 30 ? tr : 29;   // A addr clamp (B weight is zero there)
        int dyr = trc / 5, dx = trc - 5 * dyr;
        tapoff[cc] = (dyr * 68 + dx) * 8;          // in shorts
        if constexpr (TAB)
            wfrag[cc] = *reinterpret_cast<const bf16x8*>(
                &wtab[((c * 16 + m16) * 32 + tr) * 8]);
    }

    if constexpr (!TAB) {
        // fallback: build [16 n][32 tr][8 o] table in LDS beyond stage region
        unsigned short* ldsw = stage + 12288;      // bytes 24576..32768
        for (int e = tid; e < 4096; e += 256) {
            int o = e & 7, tr = (e >> 3) & 31, n16 = e >> 8;
            int t = n16 & 7, dlt = n16 >> 3;
            float w = 0.0f;
            if (tr < 30) {
                int dyr = tr / 5, dx = tr - 5 * dyr;
                int dy  = dyr - dlt;
                if (dy >= 0 && dy < 5) w = rot_w(kern, c, t, o, dy, dx);
            }
            ldsw[e] = f2bf(w);
        }
        __syncthreads();
#pragma unroll
        for (int cc = 0; cc < 8; ++cc)
            wfrag[cc] = *reinterpret_cast<const bf16x8*>(
                &ldsw[(m16 * 32 + cc * 4 + g) * 8]);
        __syncthreads();   // wfrag reads done before packch overwrites region
    }

    packch(tid, v0);
    packch(tid + 256, v1);
    packch(tid + 512, v2);
    packch(tid + 768, v3);
    packch(tid + 1024, v4);
    if (tid < 80) packch(tid + 1280, v5);
    __syncthreads();

    // ---- compute: 8 s-iters (pr = s>>2 row-pair, xq = s&3), all unrolled ----
    f32x4 acc[8];
#pragma unroll
    for (int s = 0; s < 8; ++s) {
        acc[s] = (f32x4){0.f, 0.f, 0.f, 0.f};
        const int yl = wv * 4 + (s >> 2) * 2;
        const int baseS = (yl * 68 + (s & 3) * 16 + m16) * 8;
#pragma unroll
        for (int cc = 0; cc < 8; ++cc) {
            bf16x8 xf = *reinterpret_cast<const bf16x8*>(&stage[baseS + tapoff[cc]]);
            acc[s] = __builtin_amdgcn_mfma_f32_16x16x32_bf16(xf, wfrag[cc], acc[s], 0, 0, 0);
        }
    }
    __syncthreads();   // all waves done reading stage; epil overwrites union

    // ---- wave-private epilogue: wave wv owns rows wv*4..wv*4+3 ----
    const int t_o = m16 & 7, dlt = m16 >> 3;
#pragma unroll
    for (int s = 0; s < 8; ++s) {
        int y  = wv * 4 + (s >> 2) * 2 + dlt;      // within this wave's rows
        int xx = (s & 3) * 16 + g * 4;
        *reinterpret_cast<f32x4*>(&epil[t_o * EPIL_TS + y * EPIL_RP + xx]) = acc[s];
    }
    // no barrier: reads below touch only this wave's rows (lgkmcnt orders)

    float* outb = out + (size_t)bc * 131072;
#pragma unroll
    for (int j = 0; j < 8; ++j) {
        int idx = j * 64 + lane;
        int xq  = idx & 15;            // 16 f32x4 per 64-col row
        int y4  = (idx >> 4) & 3;      // row within wave's 4
        int t   = idx >> 6;            // 0..7
        int y   = wv * 4 + y4;
        f32x4 v = *reinterpret_cast<const f32x4*>(
            &epil[t * EPIL_TS + y * EPIL_RP + xq * 4]);
        __builtin_nontemporal_store(v, reinterpret_cast<f32x4*>(
            outb + (size_t)t * 16384 + (size_t)(Y0 + y) * 128 + X0 + xq * 4));
    }
}

extern "C" void kernel_launch(void* const* d_in, const int* in_sizes, int n_in,
                              void* d_out, int out_size, void* d_ws, size_t ws_size,
                              hipStream_t stream) {
    const float* x    = (const float*)d_in[0];
    const float* kern = (const float*)d_in[1];
    float* out = (float*)d_out;
    dim3 block(256);
    if (ws_size >= 131072 * sizeof(unsigned short)) {
        unsigned short* wtab = (unsigned short*)d_ws;
        build_w2<<<dim3(512), block, 0, stream>>>(kern, wtab);
        se2_mfma<true><<<dim3(4096), block, 0, stream>>>(x, kern, wtab, out);
    } else {
        se2_mfma<false><<<dim3(4096), block, 0, stream>>>(x, kern, nullptr, out);
    }
}